// Round 1
// baseline (505.950 us; speedup 1.0000x reference)
//
#include <hip/hip_runtime.h>
#include <hip/hip_bf16.h>

// MultiHeadCausalSelfAttention: B=2, N=4096, C=512, H=8, D=64, causal, fp32 in/out.
// Pipeline: cvt(fp32->bf16) -> QKV GEMM (scatter to Q,K,Vt) -> flash attn -> proj GEMM.

typedef __attribute__((ext_vector_type(8))) short s16x8;   // 8 bf16 = one MFMA A/B frag
typedef __attribute__((ext_vector_type(4))) float f32x4;   // one MFMA C/D frag

#define QSCALE 0.18033688011112042f  // D^-0.5 * log2(e), folded into Q

__device__ __forceinline__ ushort f2bf(float f) {
  unsigned u = __float_as_uint(f);
  u = (u + 0x7FFFu + ((u >> 16) & 1u)) >> 16;  // RNE
  return (ushort)u;
}

__global__ __launch_bounds__(256) void cvt_kernel(const float* __restrict__ in,
                                                  ushort* __restrict__ out, int n4) {
  int i = blockIdx.x * 256 + threadIdx.x;
  if (i >= n4) return;
  float4 v = reinterpret_cast<const float4*>(in)[i];
  ushort4 o;
  o.x = f2bf(v.x); o.y = f2bf(v.y); o.z = f2bf(v.z); o.w = f2bf(v.w);
  reinterpret_cast<ushort4*>(out)[i] = o;
}

// C = A[M,512] @ W[Nout,512]^T, bf16 MFMA, 128x128 tile, 4 waves (2x2), BK=32.
// EPI 0: scatter to q_ws (scaled), k_ws, vt_ws (transposed).  EPI 1: fp32 out + bias.
template <int EPI>
__global__ __launch_bounds__(256) void gemm_bt(const ushort* __restrict__ A,
                                               const ushort* __restrict__ W,
                                               ushort* __restrict__ q_ws,
                                               ushort* __restrict__ k_ws,
                                               ushort* __restrict__ vt_ws,
                                               float* __restrict__ outf,
                                               const float* __restrict__ bias) {
  __shared__ ushort As[128 * 32];
  __shared__ ushort Bs[128 * 32];
  const int tid = threadIdx.x;
  const int lane = tid & 63, wv = tid >> 6;
  const int wm = wv >> 1, wn = wv & 1;
  const int l15 = lane & 15, g = lane >> 4;
  const int tm = blockIdx.y * 128, tn = blockIdx.x * 128;

  f32x4 acc[4][4] = {};

  for (int k0 = 0; k0 < 512; k0 += 32) {
#pragma unroll
    for (int it = 0; it < 2; ++it) {
      int c = tid + 256 * it;           // [0,512): 128 rows x 4 chunks of 8 bf16
      int row = c >> 2, ch = c & 3;
      int sidx = row * 4 + (ch ^ ((row >> 1) & 3));  // XOR swizzle vs 8-way conflict
      reinterpret_cast<int4*>(As)[sidx] =
          *reinterpret_cast<const int4*>(A + (size_t)(tm + row) * 512 + k0 + ch * 8);
      reinterpret_cast<int4*>(Bs)[sidx] =
          *reinterpret_cast<const int4*>(W + (size_t)(tn + row) * 512 + k0 + ch * 8);
    }
    __syncthreads();
    s16x8 af[4], bfr[4];
#pragma unroll
    for (int i = 0; i < 4; ++i) {
      int Ra = wm * 64 + i * 16 + l15;
      af[i] = reinterpret_cast<const s16x8*>(As)[Ra * 4 + (g ^ ((Ra >> 1) & 3))];
      int Rb = wn * 64 + i * 16 + l15;
      bfr[i] = reinterpret_cast<const s16x8*>(Bs)[Rb * 4 + (g ^ ((Rb >> 1) & 3))];
    }
#pragma unroll
    for (int mi = 0; mi < 4; ++mi)
#pragma unroll
      for (int ni = 0; ni < 4; ++ni)
        acc[mi][ni] =
            __builtin_amdgcn_mfma_f32_16x16x32_bf16(af[mi], bfr[ni], acc[mi][ni], 0, 0, 0);
    __syncthreads();
  }

  // C/D layout: col = lane&15, row = (lane>>4)*4 + reg   [measured m89/m91]
  const int rowb = tm + wm * 64 + g * 4;
  const int colb = tn + wn * 64 + l15;
#pragma unroll
  for (int mi = 0; mi < 4; ++mi) {
#pragma unroll
    for (int ni = 0; ni < 4; ++ni) {
      int r0 = rowb + mi * 16;
      int col = colb + ni * 16;
      if (EPI == 0) {
        int i3 = col >> 9, h = (col >> 6) & 7, d = col & 63;
        int b = r0 >> 12, n0 = r0 & 4095;
        if (i3 == 2) {  // V -> transposed [BH][D][N], pack 4 consecutive n
          ushort4 pk;
          pk.x = f2bf(acc[mi][ni][0]);
          pk.y = f2bf(acc[mi][ni][1]);
          pk.z = f2bf(acc[mi][ni][2]);
          pk.w = f2bf(acc[mi][ni][3]);
          *reinterpret_cast<ushort4*>(vt_ws + ((size_t)(b * 8 + h) * 64 + d) * 4096 + n0) = pk;
        } else {
          ushort* dst = (i3 == 0) ? q_ws : k_ws;
          float sc = (i3 == 0) ? QSCALE : 1.0f;
#pragma unroll
          for (int r = 0; r < 4; ++r)
            dst[((size_t)(b * 8 + h) * 4096 + (n0 + r)) * 64 + d] = f2bf(acc[mi][ni][r] * sc);
        }
      } else {
#pragma unroll
        for (int r = 0; r < 4; ++r)
          outf[(size_t)(r0 + r) * 512 + col] = acc[mi][ni][r] + bias[col];
      }
    }
  }
}

// Flash attention, causal. Grid (N/64, B*H). 4 waves x 16 q-rows. K/V from global (L2).
__global__ __launch_bounds__(256) void attn_kernel(const ushort* __restrict__ Q,
                                                   const ushort* __restrict__ Kk,
                                                   const ushort* __restrict__ Vt,
                                                   ushort* __restrict__ O) {
  __shared__ ushort P_lds[4][16 * 64];  // per-wave P transpose buffer
  const int tid = threadIdx.x;
  const int lane = tid & 63, wv = tid >> 6;
  const int l15 = lane & 15, g = lane >> 4;
  const int qt = (int)gridDim.x - 1 - (int)blockIdx.x;  // heavy tiles first
  const int bh = blockIdx.y;
  const int q0 = qt * 64, qw = q0 + wv * 16;
  const size_t baseQK = (size_t)bh * 4096 * 64;
  const size_t baseV = (size_t)bh * 64 * 4096;

  // Q A-frags: row = lane&15, k = (lane>>4)*8+j  (two 32-wide k chunks)
  s16x8 aq[2];
  {
    const ushort* qp = Q + baseQK + (size_t)(qw + l15) * 64 + g * 8;
    aq[0] = *reinterpret_cast<const s16x8*>(qp);
    aq[1] = *reinterpret_cast<const s16x8*>(qp + 32);
  }

  f32x4 o[4] = {};
  float m[4], l[4];
#pragma unroll
  for (int r = 0; r < 4; ++r) { m[r] = -1e30f; l[r] = 0.f; }

  ushort* pl = P_lds[wv];

  for (int kt = 0; kt <= qt; ++kt) {
    const int k0 = kt * 64;
    f32x4 s[4] = {};
#pragma unroll
    for (int nb = 0; nb < 4; ++nb) {
      const ushort* kp = Kk + baseQK + (size_t)(k0 + nb * 16 + l15) * 64 + g * 8;
      s16x8 b0 = *reinterpret_cast<const s16x8*>(kp);
      s16x8 b1 = *reinterpret_cast<const s16x8*>(kp + 32);
      s[nb] = __builtin_amdgcn_mfma_f32_16x16x32_bf16(aq[0], b0, s[nb], 0, 0, 0);
      s[nb] = __builtin_amdgcn_mfma_f32_16x16x32_bf16(aq[1], b1, s[nb], 0, 0, 0);
    }
    if (kt == qt) {  // diagonal tile: mask key > query
#pragma unroll
      for (int nb = 0; nb < 4; ++nb)
#pragma unroll
        for (int r = 0; r < 4; ++r) {
          int key = k0 + nb * 16 + l15;
          int qi = qw + g * 4 + r;
          if (key > qi) s[nb][r] = -1e30f;
        }
    }
    float mn[4], rs[4];
#pragma unroll
    for (int r = 0; r < 4; ++r) {
      float pm = fmaxf(fmaxf(s[0][r], s[1][r]), fmaxf(s[2][r], s[3][r]));
      pm = fmaxf(pm, __shfl_xor(pm, 1));
      pm = fmaxf(pm, __shfl_xor(pm, 2));
      pm = fmaxf(pm, __shfl_xor(pm, 4));
      pm = fmaxf(pm, __shfl_xor(pm, 8));
      mn[r] = fmaxf(m[r], pm);
      rs[r] = 0.f;
    }
#pragma unroll
    for (int nb = 0; nb < 4; ++nb)
#pragma unroll
      for (int r = 0; r < 4; ++r) {
        float p = exp2f(s[nb][r] - mn[r]);
        rs[r] += p;
        int row = g * 4 + r, col = nb * 16 + l15;
        pl[row * 64 + (((col >> 3) ^ (row & 7)) << 3) + (col & 7)] = f2bf(p);
      }
#pragma unroll
    for (int r = 0; r < 4; ++r) {
      float t = rs[r];
      t += __shfl_xor(t, 1);
      t += __shfl_xor(t, 2);
      t += __shfl_xor(t, 4);
      t += __shfl_xor(t, 8);
      float al = exp2f(m[r] - mn[r]);
      l[r] = l[r] * al + t;
      m[r] = mn[r];
#pragma unroll
      for (int nb = 0; nb < 4; ++nb) o[nb][r] *= al;
    }
    __syncthreads();
    s16x8 pa[2];
#pragma unroll
    for (int kc = 0; kc < 2; ++kc) {
      int cc = kc * 4 + g;
      pa[kc] = reinterpret_cast<const s16x8*>(pl)[l15 * 8 + (cc ^ (l15 & 7))];
    }
#pragma unroll
    for (int nb = 0; nb < 4; ++nb) {
      const ushort* vp = Vt + baseV + (size_t)(nb * 16 + l15) * 4096 + k0 + g * 8;
      s16x8 v0 = *reinterpret_cast<const s16x8*>(vp);
      s16x8 v1 = *reinterpret_cast<const s16x8*>(vp + 32);
      o[nb] = __builtin_amdgcn_mfma_f32_16x16x32_bf16(pa[0], v0, o[nb], 0, 0, 0);
      o[nb] = __builtin_amdgcn_mfma_f32_16x16x32_bf16(pa[1], v1, o[nb], 0, 0, 0);
    }
    __syncthreads();
  }

  const int b = bh >> 3, h = bh & 7;
#pragma unroll
  for (int nb = 0; nb < 4; ++nb)
#pragma unroll
    for (int r = 0; r < 4; ++r) {
      int qi = qw + g * 4 + r;
      float v = o[nb][r] / l[r];
      O[(size_t)(b * 4096 + qi) * 512 + h * 64 + nb * 16 + l15] = f2bf(v);
    }
}

extern "C" void kernel_launch(void* const* d_in, const int* in_sizes, int n_in,
                              void* d_out, int out_size, void* d_ws, size_t ws_size,
                              hipStream_t stream) {
  const float* x = (const float*)d_in[0];       // [2,4096,512]
  const float* w_qkv = (const float*)d_in[1];   // [1536,512]
  const float* w_proj = (const float*)d_in[2];  // [512,512]
  const float* b_proj = (const float*)d_in[3];  // [512]
  float* out = (float*)d_out;                   // [2,4096,512]

  ushort* xb = (ushort*)d_ws;                       // 8192*512
  ushort* wqkvb = xb + (size_t)8192 * 512;          // 1536*512
  ushort* wprojb = wqkvb + (size_t)1536 * 512;      // 512*512
  ushort* qws = wprojb + (size_t)512 * 512;         // 16*4096*64
  ushort* kws = qws + (size_t)16 * 4096 * 64;
  ushort* vtws = kws + (size_t)16 * 4096 * 64;
  ushort* ows = vtws + (size_t)16 * 4096 * 64;      // 8192*512

  cvt_kernel<<<4096, 256, 0, stream>>>(x, xb, 8192 * 512 / 4);
  cvt_kernel<<<768, 256, 0, stream>>>(w_qkv, wqkvb, 1536 * 512 / 4);
  cvt_kernel<<<256, 256, 0, stream>>>(w_proj, wprojb, 512 * 512 / 4);

  gemm_bt<0><<<dim3(12, 64), 256, 0, stream>>>(xb, wqkvb, qws, kws, vtws, nullptr, nullptr);

  attn_kernel<<<dim3(64, 16), 256, 0, stream>>>(qws, kws, vtws, ows);

  gemm_bt<1><<<dim3(4, 64), 256, 0, stream>>>(ows, wprojb, nullptr, nullptr, nullptr, out,
                                              b_proj);
}

// Round 2
// 499.009 us; speedup vs baseline: 1.0139x; 1.0139x over previous
//
#include <hip/hip_runtime.h>
#include <hip/hip_bf16.h>

// MultiHeadCausalSelfAttention: B=2, N=4096, C=512, H=8, D=64, causal, fp32 in/out.
// Pipeline: cvt(fp32->bf16) -> QKV GEMM (scatter to Q,K,Vt) -> flash attn -> proj GEMM.
// R2: attn rewritten — swapped QK^T (S^T), barrier-free, K ping-pong prefetch.

typedef __attribute__((ext_vector_type(8))) short s16x8;   // 8 bf16 = one MFMA A/B frag
typedef __attribute__((ext_vector_type(4))) float f32x4;   // one MFMA C/D frag

#define QSCALE 0.18033688011112042f  // D^-0.5 * log2(e), folded into Q

__device__ __forceinline__ ushort f2bf(float f) {
  unsigned u = __float_as_uint(f);
  u = (u + 0x7FFFu + ((u >> 16) & 1u)) >> 16;  // RNE
  return (ushort)u;
}

__global__ __launch_bounds__(256) void cvt_kernel(const float* __restrict__ in,
                                                  ushort* __restrict__ out, int n4) {
  int i = blockIdx.x * 256 + threadIdx.x;
  if (i >= n4) return;
  float4 v = reinterpret_cast<const float4*>(in)[i];
  ushort4 o;
  o.x = f2bf(v.x); o.y = f2bf(v.y); o.z = f2bf(v.z); o.w = f2bf(v.w);
  reinterpret_cast<ushort4*>(out)[i] = o;
}

// C = A[M,512] @ W[Nout,512]^T, bf16 MFMA, 128x128 tile, 4 waves (2x2), BK=32.
// EPI 0: scatter to q_ws (scaled), k_ws, vt_ws (transposed).  EPI 1: fp32 out + bias.
template <int EPI>
__global__ __launch_bounds__(256) void gemm_bt(const ushort* __restrict__ A,
                                               const ushort* __restrict__ W,
                                               ushort* __restrict__ q_ws,
                                               ushort* __restrict__ k_ws,
                                               ushort* __restrict__ vt_ws,
                                               float* __restrict__ outf,
                                               const float* __restrict__ bias) {
  __shared__ ushort As[128 * 32];
  __shared__ ushort Bs[128 * 32];
  const int tid = threadIdx.x;
  const int lane = tid & 63, wv = tid >> 6;
  const int wm = wv >> 1, wn = wv & 1;
  const int l15 = lane & 15, g = lane >> 4;
  const int tm = blockIdx.y * 128, tn = blockIdx.x * 128;

  f32x4 acc[4][4] = {};

  for (int k0 = 0; k0 < 512; k0 += 32) {
#pragma unroll
    for (int it = 0; it < 2; ++it) {
      int c = tid + 256 * it;           // [0,512): 128 rows x 4 chunks of 8 bf16
      int row = c >> 2, ch = c & 3;
      int sidx = row * 4 + (ch ^ ((row >> 1) & 3));  // XOR swizzle vs 8-way conflict
      reinterpret_cast<int4*>(As)[sidx] =
          *reinterpret_cast<const int4*>(A + (size_t)(tm + row) * 512 + k0 + ch * 8);
      reinterpret_cast<int4*>(Bs)[sidx] =
          *reinterpret_cast<const int4*>(W + (size_t)(tn + row) * 512 + k0 + ch * 8);
    }
    __syncthreads();
    s16x8 af[4], bfr[4];
#pragma unroll
    for (int i = 0; i < 4; ++i) {
      int Ra = wm * 64 + i * 16 + l15;
      af[i] = reinterpret_cast<const s16x8*>(As)[Ra * 4 + (g ^ ((Ra >> 1) & 3))];
      int Rb = wn * 64 + i * 16 + l15;
      bfr[i] = reinterpret_cast<const s16x8*>(Bs)[Rb * 4 + (g ^ ((Rb >> 1) & 3))];
    }
#pragma unroll
    for (int mi = 0; mi < 4; ++mi)
#pragma unroll
      for (int ni = 0; ni < 4; ++ni)
        acc[mi][ni] =
            __builtin_amdgcn_mfma_f32_16x16x32_bf16(af[mi], bfr[ni], acc[mi][ni], 0, 0, 0);
    __syncthreads();
  }

  // C/D layout: col = lane&15, row = (lane>>4)*4 + reg   [measured m89/m91]
  const int rowb = tm + wm * 64 + g * 4;
  const int colb = tn + wn * 64 + l15;
#pragma unroll
  for (int mi = 0; mi < 4; ++mi) {
#pragma unroll
    for (int ni = 0; ni < 4; ++ni) {
      int r0 = rowb + mi * 16;
      int col = colb + ni * 16;
      if (EPI == 0) {
        int i3 = col >> 9, h = (col >> 6) & 7, d = col & 63;
        int b = r0 >> 12, n0 = r0 & 4095;
        if (i3 == 2) {  // V -> transposed [BH][D][N], pack 4 consecutive n
          ushort4 pk;
          pk.x = f2bf(acc[mi][ni][0]);
          pk.y = f2bf(acc[mi][ni][1]);
          pk.z = f2bf(acc[mi][ni][2]);
          pk.w = f2bf(acc[mi][ni][3]);
          *reinterpret_cast<ushort4*>(vt_ws + ((size_t)(b * 8 + h) * 64 + d) * 4096 + n0) = pk;
        } else {
          ushort* dst = (i3 == 0) ? q_ws : k_ws;
          float sc = (i3 == 0) ? QSCALE : 1.0f;
#pragma unroll
          for (int r = 0; r < 4; ++r)
            dst[((size_t)(b * 8 + h) * 4096 + (n0 + r)) * 64 + d] = f2bf(acc[mi][ni][r] * sc);
        }
      } else {
#pragma unroll
        for (int r = 0; r < 4; ++r)
          outf[(size_t)(r0 + r) * 512 + col] = acc[mi][ni][r] + bias[col];
      }
    }
  }
}

// Flash attention, causal. Grid (N/64, B*H). 4 independent waves x 16 q-rows.
// Swapped QK^T: S^T = mfma(K_frag, Q_frag) -> lane owns query l15, 16 keys in regs.
// No __syncthreads (P buffer per-wave). K prefetched ping-pong, V issued at iter top.
__global__ __launch_bounds__(256) void attn_kernel(const ushort* __restrict__ Q,
                                                   const ushort* __restrict__ Kk,
                                                   const ushort* __restrict__ Vt,
                                                   ushort* __restrict__ O) {
  __shared__ ushort P_lds[4][16 * 64];  // per-wave P transpose buffer (swizzled)
  const int tid = threadIdx.x;
  const int lane = tid & 63, wv = tid >> 6;
  const int l15 = lane & 15, g = lane >> 4;
  const int qt = (int)gridDim.x - 1 - (int)blockIdx.x;  // heavy tiles first
  const int bh = blockIdx.y;
  const int qw = qt * 64 + wv * 16;
  const size_t baseQK = (size_t)bh * 4096 * 64;
  const size_t baseV = (size_t)bh * 64 * 4096;

  // Q B-frag (rows = queries): row = l15 -> query qw+l15; k-elems = g*8+j (+32)
  s16x8 aq0, aq1;
  {
    const ushort* qp = Q + baseQK + (size_t)(qw + l15) * 64 + g * 8;
    aq0 = *reinterpret_cast<const s16x8*>(qp);
    aq1 = *reinterpret_cast<const s16x8*>(qp + 32);
  }

  f32x4 o[4] = {};
  float m = -1e30f, l = 0.f;
  ushort* pl = P_lds[wv];
  const int swz = (l15 & 7) << 3;            // XOR swizzle, 8-ushort (16B) granules
  const int wr0 = l15 * 64;                  // row base (ushorts)
  const ushort* kbase = Kk + baseQK + (size_t)l15 * 64 + g * 8;
  const ushort* vbase = Vt + baseV + (size_t)l15 * 4096 + g * 8;

  s16x8 kA[8], kB[8];
#pragma unroll
  for (int nb = 0; nb < 4; ++nb) {
    kA[nb * 2 + 0] = *reinterpret_cast<const s16x8*>(kbase + (size_t)nb * 16 * 64);
    kA[nb * 2 + 1] = *reinterpret_cast<const s16x8*>(kbase + (size_t)nb * 16 * 64 + 32);
  }

  auto body = [&](s16x8* kc, s16x8* kn, int kt) {
    const int k0 = kt * 64;
    // prefetch next K tile (clamped; redundant load on last iter, L1/L2-hit)
    const int knx = (kt + 1 > qt ? qt : kt + 1) * 64;
#pragma unroll
    for (int nb = 0; nb < 4; ++nb) {
      const ushort* kp = kbase + (size_t)(knx + nb * 16) * 64;
      kn[nb * 2 + 0] = *reinterpret_cast<const s16x8*>(kp);
      kn[nb * 2 + 1] = *reinterpret_cast<const s16x8*>(kp + 32);
    }
    // V frags for this tile: row = d (l15 within nb block), k-elems = keys
    s16x8 vf[8];
#pragma unroll
    for (int nb = 0; nb < 4; ++nb) {
      const ushort* vp = vbase + (size_t)nb * 16 * 4096 + k0;
      vf[nb * 2 + 0] = *reinterpret_cast<const s16x8*>(vp);
      vf[nb * 2 + 1] = *reinterpret_cast<const s16x8*>(vp + 32);
    }
    // S^T: C[key][query]: col = l15 = query, row = g*4+r = key-within-16
    f32x4 s[4] = {};
#pragma unroll
    for (int nb = 0; nb < 4; ++nb) {
      s[nb] = __builtin_amdgcn_mfma_f32_16x16x32_bf16(kc[nb * 2 + 0], aq0, s[nb], 0, 0, 0);
      s[nb] = __builtin_amdgcn_mfma_f32_16x16x32_bf16(kc[nb * 2 + 1], aq1, s[nb], 0, 0, 0);
    }
    if (kt == qt) {  // diagonal: mask key > query
#pragma unroll
      for (int nb = 0; nb < 4; ++nb)
#pragma unroll
        for (int r = 0; r < 4; ++r)
          if (nb * 16 + g * 4 + r > wv * 16 + l15) s[nb][r] = -1e30f;
    }
    // row (=query l15) max over 16 regs + lanes l15+{16,32,48}
    float pm = s[0][0];
#pragma unroll
    for (int nb = 0; nb < 4; ++nb)
#pragma unroll
      for (int r = 0; r < 4; ++r) pm = fmaxf(pm, s[nb][r]);
    pm = fmaxf(pm, __shfl_xor(pm, 16));
    pm = fmaxf(pm, __shfl_xor(pm, 32));
    const float mn = fmaxf(m, pm);
    float rs = 0.f;
    uint2 w[4];
#pragma unroll
    for (int nb = 0; nb < 4; ++nb) {
      float p0 = __builtin_amdgcn_exp2f(s[nb][0] - mn);
      float p1 = __builtin_amdgcn_exp2f(s[nb][1] - mn);
      float p2 = __builtin_amdgcn_exp2f(s[nb][2] - mn);
      float p3 = __builtin_amdgcn_exp2f(s[nb][3] - mn);
      rs += (p0 + p1) + (p2 + p3);
      w[nb].x = (unsigned)f2bf(p0) | ((unsigned)f2bf(p1) << 16);
      w[nb].y = (unsigned)f2bf(p2) | ((unsigned)f2bf(p3) << 16);
    }
    rs += __shfl_xor(rs, 16);
    rs += __shfl_xor(rs, 32);
    const float al = __builtin_amdgcn_exp2f(m - mn);
    l = l * al + rs;
    m = mn;
    // write P^T -> q-major P rows (lane's row = its query l15), swizzled
#pragma unroll
    for (int nb = 0; nb < 4; ++nb)
      *reinterpret_cast<uint2*>(pl + wr0 + ((nb * 16 + g * 4) ^ swz)) = w[nb];
    // rescale O (accumulator rows are queries g*4+r; al lives at lane q)
    float alq[4];
#pragma unroll
    for (int r = 0; r < 4; ++r) alq[r] = __shfl(al, g * 4 + r);
#pragma unroll
    for (int nb = 0; nb < 4; ++nb)
#pragma unroll
      for (int r = 0; r < 4; ++r) o[nb][r] *= alq[r];
    // P A-frags: row = l15 = query, k = kc*32 + g*8 + j (keys)
    s16x8 pa0 = *reinterpret_cast<const s16x8*>(pl + wr0 + ((0 * 32 + g * 8) ^ swz));
    s16x8 pa1 = *reinterpret_cast<const s16x8*>(pl + wr0 + ((1 * 32 + g * 8) ^ swz));
#pragma unroll
    for (int nb = 0; nb < 4; ++nb) {
      o[nb] = __builtin_amdgcn_mfma_f32_16x16x32_bf16(pa0, vf[nb * 2 + 0], o[nb], 0, 0, 0);
      o[nb] = __builtin_amdgcn_mfma_f32_16x16x32_bf16(pa1, vf[nb * 2 + 1], o[nb], 0, 0, 0);
    }
  };

  int kt = 0;
  for (;;) {
    body(kA, kB, kt);
    if (++kt > qt) break;
    body(kB, kA, kt);
    if (++kt > qt) break;
  }

  // O rows are queries qw + g*4+r, cols d = nb*16+l15; l lives at lane q-idx
  const int b = bh >> 3, h = bh & 7;
  float linv[4];
#pragma unroll
  for (int r = 0; r < 4; ++r) linv[r] = 1.0f / __shfl(l, g * 4 + r);
#pragma unroll
  for (int nb = 0; nb < 4; ++nb)
#pragma unroll
    for (int r = 0; r < 4; ++r) {
      int qi = qw + g * 4 + r;
      O[(size_t)(b * 4096 + qi) * 512 + h * 64 + nb * 16 + l15] = f2bf(o[nb][r] * linv[r]);
    }
}

extern "C" void kernel_launch(void* const* d_in, const int* in_sizes, int n_in,
                              void* d_out, int out_size, void* d_ws, size_t ws_size,
                              hipStream_t stream) {
  const float* x = (const float*)d_in[0];       // [2,4096,512]
  const float* w_qkv = (const float*)d_in[1];   // [1536,512]
  const float* w_proj = (const float*)d_in[2];  // [512,512]
  const float* b_proj = (const float*)d_in[3];  // [512]
  float* out = (float*)d_out;                   // [2,4096,512]

  ushort* xb = (ushort*)d_ws;                       // 8192*512
  ushort* wqkvb = xb + (size_t)8192 * 512;          // 1536*512
  ushort* wprojb = wqkvb + (size_t)1536 * 512;      // 512*512
  ushort* qws = wprojb + (size_t)512 * 512;         // 16*4096*64
  ushort* kws = qws + (size_t)16 * 4096 * 64;
  ushort* vtws = kws + (size_t)16 * 4096 * 64;
  ushort* ows = vtws + (size_t)16 * 4096 * 64;      // 8192*512

  cvt_kernel<<<4096, 256, 0, stream>>>(x, xb, 8192 * 512 / 4);
  cvt_kernel<<<768, 256, 0, stream>>>(w_qkv, wqkvb, 1536 * 512 / 4);
  cvt_kernel<<<256, 256, 0, stream>>>(w_proj, wprojb, 512 * 512 / 4);

  gemm_bt<0><<<dim3(12, 64), 256, 0, stream>>>(xb, wqkvb, qws, kws, vtws, nullptr, nullptr);

  attn_kernel<<<dim3(64, 16), 256, 0, stream>>>(qws, kws, vtws, ows);

  gemm_bt<1><<<dim3(4, 64), 256, 0, stream>>>(ows, wprojb, nullptr, nullptr, nullptr, out,
                                              b_proj);
}

// Round 3
// 283.184 us; speedup vs baseline: 1.7866x; 1.7621x over previous
//
#include <hip/hip_runtime.h>
#include <hip/hip_bf16.h>

// MultiHeadCausalSelfAttention: B=2, N=4096, C=512, H=8, D=64, causal, fp32 in/out.
// Pipeline: cvt(fp32->bf16) -> QKV GEMM (scatter to Q,K,Vt) -> flash attn -> proj GEMM.
// R3: attn — no lambda/pointer arrays (R2 put frags in scratch: VGPR=88 < live set).
//     QBLK=32/wave (128 rows/block), plain unrolled loop, tree max, barrier-free.

typedef __attribute__((ext_vector_type(8))) short s16x8;   // 8 bf16 = one MFMA A/B frag
typedef __attribute__((ext_vector_type(4))) float f32x4;   // one MFMA C/D frag

#define QSCALE 0.18033688011112042f  // D^-0.5 * log2(e), folded into Q

__device__ __forceinline__ ushort f2bf(float f) {
  unsigned u = __float_as_uint(f);
  u = (u + 0x7FFFu + ((u >> 16) & 1u)) >> 16;  // RNE
  return (ushort)u;
}

__global__ __launch_bounds__(256) void cvt_kernel(const float* __restrict__ in,
                                                  ushort* __restrict__ out, int n4) {
  int i = blockIdx.x * 256 + threadIdx.x;
  if (i >= n4) return;
  float4 v = reinterpret_cast<const float4*>(in)[i];
  ushort4 o;
  o.x = f2bf(v.x); o.y = f2bf(v.y); o.z = f2bf(v.z); o.w = f2bf(v.w);
  reinterpret_cast<ushort4*>(out)[i] = o;
}

// C = A[M,512] @ W[Nout,512]^T, bf16 MFMA, 128x128 tile, 4 waves (2x2), BK=32.
// EPI 0: scatter to q_ws (scaled), k_ws, vt_ws (transposed).  EPI 1: fp32 out + bias.
template <int EPI>
__global__ __launch_bounds__(256) void gemm_bt(const ushort* __restrict__ A,
                                               const ushort* __restrict__ W,
                                               ushort* __restrict__ q_ws,
                                               ushort* __restrict__ k_ws,
                                               ushort* __restrict__ vt_ws,
                                               float* __restrict__ outf,
                                               const float* __restrict__ bias) {
  __shared__ ushort As[128 * 32];
  __shared__ ushort Bs[128 * 32];
  const int tid = threadIdx.x;
  const int lane = tid & 63, wv = tid >> 6;
  const int wm = wv >> 1, wn = wv & 1;
  const int l15 = lane & 15, g = lane >> 4;
  const int tm = blockIdx.y * 128, tn = blockIdx.x * 128;

  f32x4 acc[4][4] = {};

  for (int k0 = 0; k0 < 512; k0 += 32) {
#pragma unroll
    for (int it = 0; it < 2; ++it) {
      int c = tid + 256 * it;           // [0,512): 128 rows x 4 chunks of 8 bf16
      int row = c >> 2, ch = c & 3;
      int sidx = row * 4 + (ch ^ ((row >> 1) & 3));  // XOR swizzle vs 8-way conflict
      reinterpret_cast<int4*>(As)[sidx] =
          *reinterpret_cast<const int4*>(A + (size_t)(tm + row) * 512 + k0 + ch * 8);
      reinterpret_cast<int4*>(Bs)[sidx] =
          *reinterpret_cast<const int4*>(W + (size_t)(tn + row) * 512 + k0 + ch * 8);
    }
    __syncthreads();
    s16x8 af[4], bfr[4];
#pragma unroll
    for (int i = 0; i < 4; ++i) {
      int Ra = wm * 64 + i * 16 + l15;
      af[i] = reinterpret_cast<const s16x8*>(As)[Ra * 4 + (g ^ ((Ra >> 1) & 3))];
      int Rb = wn * 64 + i * 16 + l15;
      bfr[i] = reinterpret_cast<const s16x8*>(Bs)[Rb * 4 + (g ^ ((Rb >> 1) & 3))];
    }
#pragma unroll
    for (int mi = 0; mi < 4; ++mi)
#pragma unroll
      for (int ni = 0; ni < 4; ++ni)
        acc[mi][ni] =
            __builtin_amdgcn_mfma_f32_16x16x32_bf16(af[mi], bfr[ni], acc[mi][ni], 0, 0, 0);
    __syncthreads();
  }

  // C/D layout: col = lane&15, row = (lane>>4)*4 + reg   [measured m89/m91]
  const int rowb = tm + wm * 64 + g * 4;
  const int colb = tn + wn * 64 + l15;
#pragma unroll
  for (int mi = 0; mi < 4; ++mi) {
#pragma unroll
    for (int ni = 0; ni < 4; ++ni) {
      int r0 = rowb + mi * 16;
      int col = colb + ni * 16;
      if (EPI == 0) {
        int i3 = col >> 9, h = (col >> 6) & 7, d = col & 63;
        int b = r0 >> 12, n0 = r0 & 4095;
        if (i3 == 2) {  // V -> transposed [BH][D][N], pack 4 consecutive n
          ushort4 pk;
          pk.x = f2bf(acc[mi][ni][0]);
          pk.y = f2bf(acc[mi][ni][1]);
          pk.z = f2bf(acc[mi][ni][2]);
          pk.w = f2bf(acc[mi][ni][3]);
          *reinterpret_cast<ushort4*>(vt_ws + ((size_t)(b * 8 + h) * 64 + d) * 4096 + n0) = pk;
        } else {
          ushort* dst = (i3 == 0) ? q_ws : k_ws;
          float sc = (i3 == 0) ? QSCALE : 1.0f;
#pragma unroll
          for (int r = 0; r < 4; ++r)
            dst[((size_t)(b * 8 + h) * 4096 + (n0 + r)) * 64 + d] = f2bf(acc[mi][ni][r] * sc);
        }
      } else {
#pragma unroll
        for (int r = 0; r < 4; ++r)
          outf[(size_t)(r0 + r) * 512 + col] = acc[mi][ni][r] + bias[col];
      }
    }
  }
}

// Flash attention, causal. Grid (N/128, B*H). 4 independent waves x 32 q-rows.
// Swapped QK^T: S^T = mfma(K, Q) -> lane owns query l15 (per 16-row sub-tile).
// No __syncthreads; per-wave P transpose buffer in LDS (XOR-swizzled).
__global__ __launch_bounds__(256, 2) void attn_kernel(const ushort* __restrict__ Q,
                                                      const ushort* __restrict__ Kk,
                                                      const ushort* __restrict__ Vt,
                                                      ushort* __restrict__ O) {
  __shared__ ushort P_lds[4][32 * 64];  // per-wave, rows=32 queries, cols=64 keys
  const int tid = threadIdx.x;
  const int lane = tid & 63, wv = tid >> 6;
  const int l15 = lane & 15, g = lane >> 4;
  const int bqt = (int)gridDim.x - 1 - (int)blockIdx.x;  // heavy tiles first
  const int bh = blockIdx.y;
  const int qw = bqt * 128 + wv * 32;  // this wave's first query row
  const size_t baseQK = (size_t)bh * 4096 * 64;
  const size_t baseV = (size_t)bh * 64 * 4096;

  // Q B-frags (rows = queries): sub s -> query qw + s*16 + l15, k-elems g*8+j (+32)
  s16x8 aq[2][2];
#pragma unroll
  for (int s = 0; s < 2; ++s) {
    const ushort* qp = Q + baseQK + (size_t)(qw + s * 16 + l15) * 64 + g * 8;
    aq[s][0] = *reinterpret_cast<const s16x8*>(qp);
    aq[s][1] = *reinterpret_cast<const s16x8*>(qp + 32);
  }

  f32x4 o[2][4] = {};
  float m[2] = {-1e30f, -1e30f}, l[2] = {0.f, 0.f};
  ushort* pl = P_lds[wv];
  const int swz = (l15 & 7) << 3;            // XOR swizzle in ushort units (16B granule)
  const ushort* kbase = Kk + baseQK + (size_t)l15 * 64 + g * 8;
  const ushort* vbase = Vt + baseV + (size_t)l15 * 4096 + g * 8;
  const int ktmax = (qw + 31) >> 6;

  for (int kt = 0; kt <= ktmax; ++kt) {
    const int k0 = kt * 64;
    // K frags: A-rows = keys k0+nb*16+l15, k-elems = d
    s16x8 kf[8];
#pragma unroll
    for (int nb = 0; nb < 4; ++nb) {
      const ushort* kp = kbase + (size_t)(k0 + nb * 16) * 64;
      kf[nb * 2 + 0] = *reinterpret_cast<const s16x8*>(kp);
      kf[nb * 2 + 1] = *reinterpret_cast<const s16x8*>(kp + 32);
    }
    // V frags: B-rows = d (nb*16+l15), k-elems = keys k0+g*8+j (+32)
    s16x8 vf[8];
#pragma unroll
    for (int nb = 0; nb < 4; ++nb) {
      const ushort* vp = vbase + (size_t)nb * 16 * 4096 + k0;
      vf[nb * 2 + 0] = *reinterpret_cast<const s16x8*>(vp);
      vf[nb * 2 + 1] = *reinterpret_cast<const s16x8*>(vp + 32);
    }
    // S^T: C[key][query]; col=l15=query(sub), row=g*4+r=key-within-16
    f32x4 st[2][4] = {};
#pragma unroll
    for (int nb = 0; nb < 4; ++nb) {
#pragma unroll
      for (int s = 0; s < 2; ++s) {
        st[s][nb] =
            __builtin_amdgcn_mfma_f32_16x16x32_bf16(kf[nb * 2 + 0], aq[s][0], st[s][nb], 0, 0, 0);
        st[s][nb] =
            __builtin_amdgcn_mfma_f32_16x16x32_bf16(kf[nb * 2 + 1], aq[s][1], st[s][nb], 0, 0, 0);
      }
    }
    if (kt == ktmax) {  // diagonal tile: mask key > query
#pragma unroll
      for (int s = 0; s < 2; ++s)
#pragma unroll
        for (int nb = 0; nb < 4; ++nb)
#pragma unroll
          for (int r = 0; r < 4; ++r)
            if (k0 + nb * 16 + g * 4 + r > qw + s * 16 + l15) st[s][nb][r] = -1e30f;
    }
    float mn[2], al[2];
    uint2 w[2][4];
#pragma unroll
    for (int s = 0; s < 2; ++s) {
      // tree max over 16 regs, then lanes l15+{16,32}
      float a0 = fmaxf(fmaxf(st[s][0][0], st[s][0][1]), fmaxf(st[s][0][2], st[s][0][3]));
      float a1 = fmaxf(fmaxf(st[s][1][0], st[s][1][1]), fmaxf(st[s][1][2], st[s][1][3]));
      float a2 = fmaxf(fmaxf(st[s][2][0], st[s][2][1]), fmaxf(st[s][2][2], st[s][2][3]));
      float a3 = fmaxf(fmaxf(st[s][3][0], st[s][3][1]), fmaxf(st[s][3][2], st[s][3][3]));
      float pm = fmaxf(fmaxf(a0, a1), fmaxf(a2, a3));
      pm = fmaxf(pm, __shfl_xor(pm, 16));
      pm = fmaxf(pm, __shfl_xor(pm, 32));
      mn[s] = fmaxf(m[s], pm);
      float rs = 0.f;
#pragma unroll
      for (int nb = 0; nb < 4; ++nb) {
        float p0 = __builtin_amdgcn_exp2f(st[s][nb][0] - mn[s]);
        float p1 = __builtin_amdgcn_exp2f(st[s][nb][1] - mn[s]);
        float p2 = __builtin_amdgcn_exp2f(st[s][nb][2] - mn[s]);
        float p3 = __builtin_amdgcn_exp2f(st[s][nb][3] - mn[s]);
        rs += (p0 + p1) + (p2 + p3);
        w[s][nb].x = (unsigned)f2bf(p0) | ((unsigned)f2bf(p1) << 16);
        w[s][nb].y = (unsigned)f2bf(p2) | ((unsigned)f2bf(p3) << 16);
      }
      rs += __shfl_xor(rs, 16);
      rs += __shfl_xor(rs, 32);
      al[s] = __builtin_amdgcn_exp2f(m[s] - mn[s]);
      l[s] = l[s] * al[s] + rs;
      m[s] = mn[s];
    }
    // write P^T -> q-major rows (row = sub*16 + l15 = lane's query), swizzled
#pragma unroll
    for (int s = 0; s < 2; ++s)
#pragma unroll
      for (int nb = 0; nb < 4; ++nb)
        *reinterpret_cast<uint2*>(pl + (s * 16 + l15) * 64 + ((nb * 16 + g * 4) ^ swz)) =
            w[s][nb];
    // rescale O: acc rows are queries sub*16 + g*4 + r; al lives at lane == query idx
#pragma unroll
    for (int s = 0; s < 2; ++s) {
      float alq[4];
#pragma unroll
      for (int r = 0; r < 4; ++r) alq[r] = __shfl(al[s], g * 4 + r);
#pragma unroll
      for (int nb = 0; nb < 4; ++nb)
#pragma unroll
        for (int r = 0; r < 4; ++r) o[s][nb][r] *= alq[r];
    }
    // P A-frags: row = l15 = query (per sub), k = kc*32 + g*8 + j (keys)
    s16x8 pa[2][2];
#pragma unroll
    for (int s = 0; s < 2; ++s)
#pragma unroll
      for (int kc = 0; kc < 2; ++kc)
        pa[s][kc] = *reinterpret_cast<const s16x8*>(pl + (s * 16 + l15) * 64 +
                                                    ((kc * 32 + g * 8) ^ swz));
#pragma unroll
    for (int nb = 0; nb < 4; ++nb)
#pragma unroll
      for (int s = 0; s < 2; ++s) {
        o[s][nb] = __builtin_amdgcn_mfma_f32_16x16x32_bf16(pa[s][0], vf[nb * 2 + 0],
                                                           o[s][nb], 0, 0, 0);
        o[s][nb] = __builtin_amdgcn_mfma_f32_16x16x32_bf16(pa[s][1], vf[nb * 2 + 1],
                                                           o[s][nb], 0, 0, 0);
      }
  }

  // O rows are queries qw + s*16 + g*4 + r, cols d = nb*16 + l15
  const int b = bh >> 3, h = bh & 7;
#pragma unroll
  for (int s = 0; s < 2; ++s) {
    float linv[4];
#pragma unroll
    for (int r = 0; r < 4; ++r) linv[r] = 1.0f / __shfl(l[s], g * 4 + r);
#pragma unroll
    for (int nb = 0; nb < 4; ++nb)
#pragma unroll
      for (int r = 0; r < 4; ++r) {
        int qi = qw + s * 16 + g * 4 + r;
        O[(size_t)(b * 4096 + qi) * 512 + h * 64 + nb * 16 + l15] =
            f2bf(o[s][nb][r] * linv[r]);
      }
  }
}

extern "C" void kernel_launch(void* const* d_in, const int* in_sizes, int n_in,
                              void* d_out, int out_size, void* d_ws, size_t ws_size,
                              hipStream_t stream) {
  const float* x = (const float*)d_in[0];       // [2,4096,512]
  const float* w_qkv = (const float*)d_in[1];   // [1536,512]
  const float* w_proj = (const float*)d_in[2];  // [512,512]
  const float* b_proj = (const float*)d_in[3];  // [512]
  float* out = (float*)d_out;                   // [2,4096,512]

  ushort* xb = (ushort*)d_ws;                       // 8192*512
  ushort* wqkvb = xb + (size_t)8192 * 512;          // 1536*512
  ushort* wprojb = wqkvb + (size_t)1536 * 512;      // 512*512
  ushort* qws = wprojb + (size_t)512 * 512;         // 16*4096*64
  ushort* kws = qws + (size_t)16 * 4096 * 64;
  ushort* vtws = kws + (size_t)16 * 4096 * 64;
  ushort* ows = vtws + (size_t)16 * 4096 * 64;      // 8192*512

  cvt_kernel<<<4096, 256, 0, stream>>>(x, xb, 8192 * 512 / 4);
  cvt_kernel<<<768, 256, 0, stream>>>(w_qkv, wqkvb, 1536 * 512 / 4);
  cvt_kernel<<<256, 256, 0, stream>>>(w_proj, wprojb, 512 * 512 / 4);

  gemm_bt<0><<<dim3(12, 64), 256, 0, stream>>>(xb, wqkvb, qws, kws, vtws, nullptr, nullptr);

  attn_kernel<<<dim3(32, 16), 256, 0, stream>>>(qws, kws, vtws, ows);

  gemm_bt<1><<<dim3(4, 64), 256, 0, stream>>>(ows, wprojb, nullptr, nullptr, nullptr, out,
                                              b_proj);
}

// Round 4
// 195.548 us; speedup vs baseline: 2.5873x; 1.4482x over previous
//
#include <hip/hip_runtime.h>
#include <hip/hip_bf16.h>

// MultiHeadCausalSelfAttention: B=2, N=4096, C=512, H=8, D=64, causal, fp32 in/out.
// Pipeline: cvt(fp32->bf16) -> QKV GEMM (scatter Q, frag-layout K/V) -> attn -> proj.
// R4: frag-contiguous K/V loads; O^T PV (scalar rescale); defer-max; 1-wave blocks.

typedef __attribute__((ext_vector_type(8))) short s16x8;   // 8 bf16 = one MFMA A/B frag
typedef __attribute__((ext_vector_type(4))) float f32x4;   // one MFMA C/D frag

#define QSCALE 0.18033688011112042f  // D^-0.5 * log2(e), folded into Q

__device__ __forceinline__ ushort f2bf(float f) {
  unsigned u = __float_as_uint(f);
  u = (u + 0x7FFFu + ((u >> 16) & 1u)) >> 16;  // RNE
  return (ushort)u;
}

__global__ __launch_bounds__(256) void cvt_kernel(const float* __restrict__ in,
                                                  ushort* __restrict__ out, int n4) {
  int i = blockIdx.x * 256 + threadIdx.x;
  if (i >= n4) return;
  float4 v = reinterpret_cast<const float4*>(in)[i];
  ushort4 o;
  o.x = f2bf(v.x); o.y = f2bf(v.y); o.z = f2bf(v.z); o.w = f2bf(v.w);
  reinterpret_cast<ushort4*>(out)[i] = o;
}

// C = A[M,512] @ W[Nout,512]^T, bf16 MFMA, 128x128 tile, 4 waves (2x2), BK=32.
// EPI 0: Q -> [bh][n][d] (scaled); K,V -> fragment-contiguous tiles (see attn loads).
// EPI 1: fp32 out + bias.
template <int EPI>
__global__ __launch_bounds__(256) void gemm_bt(const ushort* __restrict__ A,
                                               const ushort* __restrict__ W,
                                               ushort* __restrict__ q_ws,
                                               ushort* __restrict__ k_ws,
                                               ushort* __restrict__ vt_ws,
                                               float* __restrict__ outf,
                                               const float* __restrict__ bias) {
  __shared__ ushort As[128 * 32];
  __shared__ ushort Bs[128 * 32];
  const int tid = threadIdx.x;
  const int lane = tid & 63, wv = tid >> 6;
  const int wm = wv >> 1, wn = wv & 1;
  const int l15 = lane & 15, g = lane >> 4;
  const int tm = blockIdx.y * 128, tn = blockIdx.x * 128;

  f32x4 acc[4][4] = {};

  for (int k0 = 0; k0 < 512; k0 += 32) {
#pragma unroll
    for (int it = 0; it < 2; ++it) {
      int c = tid + 256 * it;           // [0,512): 128 rows x 4 chunks of 8 bf16
      int row = c >> 2, ch = c & 3;
      int sidx = row * 4 + (ch ^ ((row >> 1) & 3));  // XOR swizzle vs 8-way conflict
      reinterpret_cast<int4*>(As)[sidx] =
          *reinterpret_cast<const int4*>(A + (size_t)(tm + row) * 512 + k0 + ch * 8);
      reinterpret_cast<int4*>(Bs)[sidx] =
          *reinterpret_cast<const int4*>(W + (size_t)(tn + row) * 512 + k0 + ch * 8);
    }
    __syncthreads();
    s16x8 af[4], bfr[4];
#pragma unroll
    for (int i = 0; i < 4; ++i) {
      int Ra = wm * 64 + i * 16 + l15;
      af[i] = reinterpret_cast<const s16x8*>(As)[Ra * 4 + (g ^ ((Ra >> 1) & 3))];
      int Rb = wn * 64 + i * 16 + l15;
      bfr[i] = reinterpret_cast<const s16x8*>(Bs)[Rb * 4 + (g ^ ((Rb >> 1) & 3))];
    }
#pragma unroll
    for (int mi = 0; mi < 4; ++mi)
#pragma unroll
      for (int ni = 0; ni < 4; ++ni)
        acc[mi][ni] =
            __builtin_amdgcn_mfma_f32_16x16x32_bf16(af[mi], bfr[ni], acc[mi][ni], 0, 0, 0);
    __syncthreads();
  }

  // C/D layout: col = lane&15, row = (lane>>4)*4 + reg   [measured m89/m91]
  const int rowb = tm + wm * 64 + g * 4;
  const int colb = tn + wn * 64 + l15;
#pragma unroll
  for (int mi = 0; mi < 4; ++mi) {
#pragma unroll
    for (int ni = 0; ni < 4; ++ni) {
      int r0 = rowb + mi * 16;
      int col = colb + ni * 16;
      if (EPI == 0) {
        int i3 = col >> 9, h = (col >> 6) & 7, d = col & 63;
        int b = r0 >> 12;
        int bh = b * 8 + h;
        if (i3 == 2) {
          // V frag layout: idx = ((bh*64+kt)*8 + nb*2+c)*512 + (g*16+l15)*8 + j
          // with d = nb*16+l15, n = kt*64 + c*32 + g*8 + j.  4 consecutive n -> ushort4.
          int n0 = r0 & 4095;
          int kt = n0 >> 6, ce = (n0 >> 5) & 1, ge = (n0 >> 3) & 3, je = n0 & 7;
          int nbe = d >> 4, le = d & 15;
          ushort4 pk;
          pk.x = f2bf(acc[mi][ni][0]);
          pk.y = f2bf(acc[mi][ni][1]);
          pk.z = f2bf(acc[mi][ni][2]);
          pk.w = f2bf(acc[mi][ni][3]);
          *reinterpret_cast<ushort4*>(
              vt_ws + (((size_t)bh * 64 + kt) * 8 + nbe * 2 + ce) * 512 + (ge * 16 + le) * 8 +
              je) = pk;
        } else if (i3 == 1) {
          // K frag layout: idx = ((bh*64+kt)*8 + nb*2+c)*512 + (g*16+l15)*8 + j
          // with n = kt*64+nb*16+l15, d = c*32+g*8+j.
          int ce = d >> 5, ge = (d >> 3) & 3, je = d & 7;
#pragma unroll
          for (int r = 0; r < 4; ++r) {
            int n = (r0 + r) & 4095;
            int kt = n >> 6, le = n & 15, nbe = (n >> 4) & 3;
            k_ws[(((size_t)bh * 64 + kt) * 8 + nbe * 2 + ce) * 512 + (ge * 16 + le) * 8 + je] =
                f2bf(acc[mi][ni][r]);
          }
        } else {
          int n0 = r0 & 4095;
#pragma unroll
          for (int r = 0; r < 4; ++r)
            q_ws[((size_t)bh * 4096 + (n0 + r)) * 64 + d] = f2bf(acc[mi][ni][r] * QSCALE);
        }
      } else {
#pragma unroll
        for (int r = 0; r < 4; ++r)
          outf[(size_t)(r0 + r) * 512 + col] = acc[mi][ni][r] + bias[col];
      }
    }
  }
}

// Flash attention, causal. Grid (N/32, B*H), 64-thread (1-wave) blocks, QBLK=32.
// Swapped QK^T (S^T) and swapped PV (O^T): lane owns one query -> scalar m,l,rescale.
// K/V read via fragment-contiguous tiles (fully coalesced 1KB wave-loads).
__global__ __launch_bounds__(64, 3) void attn_kernel(const ushort* __restrict__ Q,
                                                     const ushort* __restrict__ Kk,
                                                     const ushort* __restrict__ Vt,
                                                     ushort* __restrict__ O) {
  __shared__ ushort P_lds[32 * 64];  // rows = 32 queries, cols = 64 keys (swizzled)
  const int lane = threadIdx.x & 63;
  const int l15 = lane & 15, g = lane >> 4;
  const int bqt = (int)gridDim.x - 1 - (int)blockIdx.x;  // heavy tiles first
  const int bh = blockIdx.y;
  const int qw = bqt * 32;
  const size_t baseQ = (size_t)bh * 4096 * 64;

  // Q B-frags: sub s -> query qw + s*16 + l15, k-elems c*32 + g*8 + j
  s16x8 aq[2][2];
#pragma unroll
  for (int s = 0; s < 2; ++s) {
    const ushort* qp = Q + baseQ + (size_t)(qw + s * 16 + l15) * 64 + g * 8;
    aq[s][0] = *reinterpret_cast<const s16x8*>(qp);
    aq[s][1] = *reinterpret_cast<const s16x8*>(qp + 32);
  }

  f32x4 o[2][4] = {};
  float m[2] = {-1e30f, -1e30f}, l[2] = {0.f, 0.f};
  const int swz = (l15 & 7) << 3;  // XOR swizzle in ushort units (16B granule)
  const ushort* kb = Kk + ((size_t)bh * 64) * 4096 + lane * 8;
  const ushort* vb = Vt + ((size_t)bh * 64) * 4096 + lane * 8;
  const int ktmax = (qw + 31) >> 6;

  for (int kt = 0; kt <= ktmax; ++kt) {
    const ushort* kp = kb + (size_t)kt * 4096;
    const ushort* vp = vb + (size_t)kt * 4096;
    // K frags (A for S^T): kf[nb*2+c] = K[k0+nb*16+l15][c*32+g*8+j], contiguous loads
    s16x8 kf[8], vf[8];
#pragma unroll
    for (int t = 0; t < 8; ++t) kf[t] = *reinterpret_cast<const s16x8*>(kp + t * 512);
    // V frags (A for O^T): vf[nb*2+c] = Vt[nb*16+l15][k0+c*32+g*8+j]
#pragma unroll
    for (int t = 0; t < 8; ++t) vf[t] = *reinterpret_cast<const s16x8*>(vp + t * 512);
    // S^T: col = l15 = query(sub), row = g*4+r = key-within-16 (+nb*16)
    f32x4 st[2][4] = {};
#pragma unroll
    for (int nb = 0; nb < 4; ++nb)
#pragma unroll
      for (int s = 0; s < 2; ++s) {
        st[s][nb] =
            __builtin_amdgcn_mfma_f32_16x16x32_bf16(kf[nb * 2 + 0], aq[s][0], st[s][nb], 0, 0, 0);
        st[s][nb] =
            __builtin_amdgcn_mfma_f32_16x16x32_bf16(kf[nb * 2 + 1], aq[s][1], st[s][nb], 0, 0, 0);
      }
    if (kt == ktmax) {  // diagonal tile: mask key > query
      const int k0 = kt * 64;
#pragma unroll
      for (int s = 0; s < 2; ++s)
#pragma unroll
        for (int nb = 0; nb < 4; ++nb)
#pragma unroll
          for (int r = 0; r < 4; ++r)
            if (k0 + nb * 16 + g * 4 + r > qw + s * 16 + l15) st[s][nb][r] = -1e30f;
    }
#pragma unroll
    for (int s = 0; s < 2; ++s) {
      // row max: tree over 16 regs, then lanes xor 16,32 (pm same across g-copies)
      float a0 = fmaxf(fmaxf(st[s][0][0], st[s][0][1]), fmaxf(st[s][0][2], st[s][0][3]));
      float a1 = fmaxf(fmaxf(st[s][1][0], st[s][1][1]), fmaxf(st[s][1][2], st[s][1][3]));
      float a2 = fmaxf(fmaxf(st[s][2][0], st[s][2][1]), fmaxf(st[s][2][2], st[s][2][3]));
      float a3 = fmaxf(fmaxf(st[s][3][0], st[s][3][1]), fmaxf(st[s][3][2], st[s][3][3]));
      float pm = fmaxf(fmaxf(a0, a1), fmaxf(a2, a3));
      pm = fmaxf(pm, __shfl_xor(pm, 16));
      pm = fmaxf(pm, __shfl_xor(pm, 32));
      // defer-max: if no lane's max grew past m+8, keep old m, skip O rescale
      const bool grew = !__all(pm - m[s] <= 8.0f);
      float mn = grew ? fmaxf(m[s], pm) : m[s];
      float rs = 0.f;
      uint2 w[4];
#pragma unroll
      for (int nb = 0; nb < 4; ++nb) {
        float p0 = __builtin_amdgcn_exp2f(st[s][nb][0] - mn);
        float p1 = __builtin_amdgcn_exp2f(st[s][nb][1] - mn);
        float p2 = __builtin_amdgcn_exp2f(st[s][nb][2] - mn);
        float p3 = __builtin_amdgcn_exp2f(st[s][nb][3] - mn);
        rs += (p0 + p1) + (p2 + p3);
        w[nb].x = (unsigned)f2bf(p0) | ((unsigned)f2bf(p1) << 16);
        w[nb].y = (unsigned)f2bf(p2) | ((unsigned)f2bf(p3) << 16);
      }
      rs += __shfl_xor(rs, 16);
      rs += __shfl_xor(rs, 32);
      if (grew) {
        const float al = __builtin_amdgcn_exp2f(m[s] - mn);
        l[s] = l[s] * al + rs;
        m[s] = mn;
        // O^T: every reg of this lane belongs to query l15 -> scalar rescale
#pragma unroll
        for (int nb = 0; nb < 4; ++nb)
#pragma unroll
          for (int r = 0; r < 4; ++r) o[s][nb][r] *= al;
      } else {
        l[s] += rs;
      }
      // write P^T -> q-major rows (row = s*16 + l15 = lane's query), swizzled
#pragma unroll
      for (int nb = 0; nb < 4; ++nb)
        *reinterpret_cast<uint2*>(P_lds + (s * 16 + l15) * 64 + ((nb * 16 + g * 4) ^ swz)) =
            w[nb];
    }
    // P B-frags (P^T): col = l15 = query, k = c*32 + g*8 + j (keys) — same regs as A(P)
    s16x8 pa[2][2];
#pragma unroll
    for (int s = 0; s < 2; ++s)
#pragma unroll
      for (int c = 0; c < 2; ++c)
        pa[s][c] = *reinterpret_cast<const s16x8*>(P_lds + (s * 16 + l15) * 64 +
                                                   ((c * 32 + g * 8) ^ swz));
    // O^T[d][q] += V^T * P^T: A = vf (rows = d), B = pa -> col = l15 = query
#pragma unroll
    for (int nb = 0; nb < 4; ++nb)
#pragma unroll
      for (int s = 0; s < 2; ++s) {
        o[s][nb] = __builtin_amdgcn_mfma_f32_16x16x32_bf16(vf[nb * 2 + 0], pa[s][0],
                                                           o[s][nb], 0, 0, 0);
        o[s][nb] = __builtin_amdgcn_mfma_f32_16x16x32_bf16(vf[nb * 2 + 1], pa[s][1],
                                                           o[s][nb], 0, 0, 0);
      }
  }

  // O^T: lane owns query qw + s*16 + l15; d = nb*16 + g*4 + r -> ushort4 stores
  const int b = bh >> 3, h = bh & 7;
#pragma unroll
  for (int s = 0; s < 2; ++s) {
    const float linv = 1.0f / l[s];
    const size_t rowo = (size_t)(b * 4096 + qw + s * 16 + l15) * 512 + h * 64;
#pragma unroll
    for (int nb = 0; nb < 4; ++nb) {
      ushort4 pk;
      pk.x = f2bf(o[s][nb][0] * linv);
      pk.y = f2bf(o[s][nb][1] * linv);
      pk.z = f2bf(o[s][nb][2] * linv);
      pk.w = f2bf(o[s][nb][3] * linv);
      *reinterpret_cast<ushort4*>(&O[rowo + nb * 16 + g * 4]) = pk;
    }
  }
}

extern "C" void kernel_launch(void* const* d_in, const int* in_sizes, int n_in,
                              void* d_out, int out_size, void* d_ws, size_t ws_size,
                              hipStream_t stream) {
  const float* x = (const float*)d_in[0];       // [2,4096,512]
  const float* w_qkv = (const float*)d_in[1];   // [1536,512]
  const float* w_proj = (const float*)d_in[2];  // [512,512]
  const float* b_proj = (const float*)d_in[3];  // [512]
  float* out = (float*)d_out;                   // [2,4096,512]

  ushort* xb = (ushort*)d_ws;                       // 8192*512
  ushort* wqkvb = xb + (size_t)8192 * 512;          // 1536*512
  ushort* wprojb = wqkvb + (size_t)1536 * 512;      // 512*512
  ushort* qws = wprojb + (size_t)512 * 512;         // 16*4096*64
  ushort* kws = qws + (size_t)16 * 4096 * 64;
  ushort* vtws = kws + (size_t)16 * 4096 * 64;
  ushort* ows = vtws + (size_t)16 * 4096 * 64;      // 8192*512

  cvt_kernel<<<4096, 256, 0, stream>>>(x, xb, 8192 * 512 / 4);
  cvt_kernel<<<768, 256, 0, stream>>>(w_qkv, wqkvb, 1536 * 512 / 4);
  cvt_kernel<<<256, 256, 0, stream>>>(w_proj, wprojb, 512 * 512 / 4);

  gemm_bt<0><<<dim3(12, 64), 256, 0, stream>>>(xb, wqkvb, qws, kws, vtws, nullptr, nullptr);

  attn_kernel<<<dim3(128, 16), 64, 0, stream>>>(qws, kws, vtws, ows);

  gemm_bt<1><<<dim3(4, 64), 256, 0, stream>>>(ows, wprojb, nullptr, nullptr, nullptr, out,
                                              b_proj);
}

// Round 5
// 145.511 us; speedup vs baseline: 3.4771x; 1.3439x over previous
//
#include <hip/hip_runtime.h>
#include <hip/hip_bf16.h>

// MultiHeadCausalSelfAttention: B=2, N=4096, C=512, H=8, D=64, causal, fp32 in/out.
// Pipeline: cvt(fp32->bf16) -> QKV GEMM (scatter Q, frag-layout K/V) -> attn -> proj.
// R5: steady-state softmax has ZERO cross-lane ops (lane-local defer-max vote +
//     per-lane partial l); v_cvt_pk_bf16_f32 packing; K ping-pong prefetch via macro.

typedef __attribute__((ext_vector_type(8))) short s16x8;   // 8 bf16 = one MFMA A/B frag
typedef __attribute__((ext_vector_type(4))) float f32x4;   // one MFMA C/D frag

#define QSCALE 0.18033688011112042f  // D^-0.5 * log2(e), folded into Q

__device__ __forceinline__ ushort f2bf(float f) {
  unsigned u = __float_as_uint(f);
  u = (u + 0x7FFFu + ((u >> 16) & 1u)) >> 16;  // RNE
  return (ushort)u;
}

__device__ __forceinline__ unsigned cvt_pk_bf16(float a, float b) {
  unsigned r;
  asm("v_cvt_pk_bf16_f32 %0, %1, %2" : "=v"(r) : "v"(a), "v"(b));
  return r;  // low16 = bf16(a), high16 = bf16(b)
}

__global__ __launch_bounds__(256) void cvt_kernel(const float* __restrict__ in,
                                                  ushort* __restrict__ out, int n4) {
  int i = blockIdx.x * 256 + threadIdx.x;
  if (i >= n4) return;
  float4 v = reinterpret_cast<const float4*>(in)[i];
  ushort4 o;
  o.x = f2bf(v.x); o.y = f2bf(v.y); o.z = f2bf(v.z); o.w = f2bf(v.w);
  reinterpret_cast<ushort4*>(out)[i] = o;
}

// C = A[M,512] @ W[Nout,512]^T, bf16 MFMA, 128x128 tile, 4 waves (2x2), BK=32.
// EPI 0: Q -> [bh][n][d] (scaled); K,V -> fragment-contiguous tiles (see attn loads).
// EPI 1: fp32 out + bias.
template <int EPI>
__global__ __launch_bounds__(256) void gemm_bt(const ushort* __restrict__ A,
                                               const ushort* __restrict__ W,
                                               ushort* __restrict__ q_ws,
                                               ushort* __restrict__ k_ws,
                                               ushort* __restrict__ vt_ws,
                                               float* __restrict__ outf,
                                               const float* __restrict__ bias) {
  __shared__ ushort As[128 * 32];
  __shared__ ushort Bs[128 * 32];
  const int tid = threadIdx.x;
  const int lane = tid & 63, wv = tid >> 6;
  const int wm = wv >> 1, wn = wv & 1;
  const int l15 = lane & 15, g = lane >> 4;
  const int tm = blockIdx.y * 128, tn = blockIdx.x * 128;

  f32x4 acc[4][4] = {};

  for (int k0 = 0; k0 < 512; k0 += 32) {
#pragma unroll
    for (int it = 0; it < 2; ++it) {
      int c = tid + 256 * it;           // [0,512): 128 rows x 4 chunks of 8 bf16
      int row = c >> 2, ch = c & 3;
      int sidx = row * 4 + (ch ^ ((row >> 1) & 3));  // XOR swizzle vs 8-way conflict
      reinterpret_cast<int4*>(As)[sidx] =
          *reinterpret_cast<const int4*>(A + (size_t)(tm + row) * 512 + k0 + ch * 8);
      reinterpret_cast<int4*>(Bs)[sidx] =
          *reinterpret_cast<const int4*>(W + (size_t)(tn + row) * 512 + k0 + ch * 8);
    }
    __syncthreads();
    s16x8 af[4], bfr[4];
#pragma unroll
    for (int i = 0; i < 4; ++i) {
      int Ra = wm * 64 + i * 16 + l15;
      af[i] = reinterpret_cast<const s16x8*>(As)[Ra * 4 + (g ^ ((Ra >> 1) & 3))];
      int Rb = wn * 64 + i * 16 + l15;
      bfr[i] = reinterpret_cast<const s16x8*>(Bs)[Rb * 4 + (g ^ ((Rb >> 1) & 3))];
    }
#pragma unroll
    for (int mi = 0; mi < 4; ++mi)
#pragma unroll
      for (int ni = 0; ni < 4; ++ni)
        acc[mi][ni] =
            __builtin_amdgcn_mfma_f32_16x16x32_bf16(af[mi], bfr[ni], acc[mi][ni], 0, 0, 0);
    __syncthreads();
  }

  // C/D layout: col = lane&15, row = (lane>>4)*4 + reg   [measured m89/m91]
  const int rowb = tm + wm * 64 + g * 4;
  const int colb = tn + wn * 64 + l15;
#pragma unroll
  for (int mi = 0; mi < 4; ++mi) {
#pragma unroll
    for (int ni = 0; ni < 4; ++ni) {
      int r0 = rowb + mi * 16;
      int col = colb + ni * 16;
      if (EPI == 0) {
        int i3 = col >> 9, h = (col >> 6) & 7, d = col & 63;
        int b = r0 >> 12;
        int bh = b * 8 + h;
        if (i3 == 2) {
          // V frag layout: idx = ((bh*64+kt)*8 + nb*2+c)*512 + lane*8 + j
          // with d = nb*16+l15, n = kt*64 + c*32 + g*8 + j.  4 consecutive n -> ushort4.
          int n0 = r0 & 4095;
          int kt = n0 >> 6, ce = (n0 >> 5) & 1, ge = (n0 >> 3) & 3, je = n0 & 7;
          int nbe = d >> 4, le = d & 15;
          ushort4 pk;
          pk.x = f2bf(acc[mi][ni][0]);
          pk.y = f2bf(acc[mi][ni][1]);
          pk.z = f2bf(acc[mi][ni][2]);
          pk.w = f2bf(acc[mi][ni][3]);
          *reinterpret_cast<ushort4*>(
              vt_ws + (((size_t)bh * 64 + kt) * 8 + nbe * 2 + ce) * 512 + (ge * 16 + le) * 8 +
              je) = pk;
        } else if (i3 == 1) {
          // K frag layout: idx = ((bh*64+kt)*8 + nb*2+c)*512 + lane*8 + j
          // with n = kt*64+nb*16+l15, d = c*32+g*8+j.
          int ce = d >> 5, ge = (d >> 3) & 3, je = d & 7;
#pragma unroll
          for (int r = 0; r < 4; ++r) {
            int n = (r0 + r) & 4095;
            int kt = n >> 6, le = n & 15, nbe = (n >> 4) & 3;
            k_ws[(((size_t)bh * 64 + kt) * 8 + nbe * 2 + ce) * 512 + (ge * 16 + le) * 8 + je] =
                f2bf(acc[mi][ni][r]);
          }
        } else {
          int n0 = r0 & 4095;
#pragma unroll
          for (int r = 0; r < 4; ++r)
            q_ws[((size_t)bh * 4096 + (n0 + r)) * 64 + d] = f2bf(acc[mi][ni][r] * QSCALE);
        }
      } else {
#pragma unroll
        for (int r = 0; r < 4; ++r)
          outf[(size_t)(r0 + r) * 512 + col] = acc[mi][ni][r] + bias[col];
      }
    }
  }
}

// Flash attention, causal. Grid (N/32, B*H), 64-thread (1-wave) blocks, QBLK=32.
// Swapped QK^T (S^T) and swapped PV (O^T). Steady state: no cross-lane ops.
// K ping-pong prefetch (macro, constant-index arrays only).
__global__ __launch_bounds__(64, 2) void attn_kernel(const ushort* __restrict__ Q,
                                                     const ushort* __restrict__ Kk,
                                                     const ushort* __restrict__ Vt,
                                                     ushort* __restrict__ O) {
  __shared__ ushort P_lds[32 * 64];  // rows = 32 queries, cols = 64 keys (swizzled)
  const int lane = threadIdx.x & 63;
  const int l15 = lane & 15, g = lane >> 4;
  const int bqt = (int)gridDim.x - 1 - (int)blockIdx.x;  // heavy tiles first
  const int bh = blockIdx.y;
  const int qw = bqt * 32;
  const size_t baseQ = (size_t)bh * 4096 * 64;

  // Q B-frags: sub s -> query qw + s*16 + l15, k-elems c*32 + g*8 + j
  s16x8 aq[2][2];
#pragma unroll
  for (int s = 0; s < 2; ++s) {
    const ushort* qp = Q + baseQ + (size_t)(qw + s * 16 + l15) * 64 + g * 8;
    aq[s][0] = *reinterpret_cast<const s16x8*>(qp);
    aq[s][1] = *reinterpret_cast<const s16x8*>(qp + 32);
  }

  f32x4 o[2][4] = {};
  float m[2] = {-1e30f, -1e30f};
  float l[2] = {0.f, 0.f};  // per-lane PARTIAL sums (reduced in epilogue)
  const int swz = (l15 & 7) << 3;  // XOR swizzle in ushort units (16B granule)
  const ushort* kb = Kk + ((size_t)bh * 64) * 4096 + lane * 8;
  const ushort* vb = Vt + ((size_t)bh * 64) * 4096 + lane * 8;
  const int ktmax = (qw + 31) >> 6;

  s16x8 kfA[8], kfB[8];
#pragma unroll
  for (int t = 0; t < 8; ++t) kfA[t] = *reinterpret_cast<const s16x8*>(kb + t * 512);

#define ATTN_STEP(KC, KN, KT)                                                             \
  do {                                                                                    \
    const int knx = ((KT) >= ktmax) ? ktmax : ((KT) + 1);                                 \
    const ushort* kpn = kb + (size_t)knx * 4096;                                          \
    _Pragma("unroll") for (int t = 0; t < 8; ++t)                                         \
        KN[t] = *reinterpret_cast<const s16x8*>(kpn + t * 512);                           \
    const ushort* vp = vb + (size_t)(KT) * 4096;                                          \
    s16x8 vf[8];                                                                          \
    _Pragma("unroll") for (int t = 0; t < 8; ++t)                                         \
        vf[t] = *reinterpret_cast<const s16x8*>(vp + t * 512);                            \
    f32x4 st[2][4] = {};                                                                  \
    _Pragma("unroll") for (int nb = 0; nb < 4; ++nb) {                                    \
      _Pragma("unroll") for (int s = 0; s < 2; ++s) {                                     \
        st[s][nb] = __builtin_amdgcn_mfma_f32_16x16x32_bf16(KC[nb * 2 + 0], aq[s][0],     \
                                                            st[s][nb], 0, 0, 0);         \
        st[s][nb] = __builtin_amdgcn_mfma_f32_16x16x32_bf16(KC[nb * 2 + 1], aq[s][1],     \
                                                            st[s][nb], 0, 0, 0);         \
      }                                                                                   \
    }                                                                                     \
    if ((KT) == ktmax) { /* diagonal: mask key > query */                                 \
      const int k0d = (KT) * 64;                                                          \
      _Pragma("unroll") for (int s = 0; s < 2; ++s)                                       \
          _Pragma("unroll") for (int nb = 0; nb < 4; ++nb)                                \
              _Pragma("unroll") for (int r = 0; r < 4; ++r)                               \
                  if (k0d + nb * 16 + g * 4 + r > qw + s * 16 + l15)                      \
                    st[s][nb][r] = -1e30f;                                                \
    }                                                                                     \
    _Pragma("unroll") for (int s = 0; s < 2; ++s) {                                       \
      float a0 = fmaxf(fmaxf(st[s][0][0], st[s][0][1]), fmaxf(st[s][0][2], st[s][0][3])); \
      float a1 = fmaxf(fmaxf(st[s][1][0], st[s][1][1]), fmaxf(st[s][1][2], st[s][1][3])); \
      float a2 = fmaxf(fmaxf(st[s][2][0], st[s][2][1]), fmaxf(st[s][2][2], st[s][2][3])); \
      float a3 = fmaxf(fmaxf(st[s][3][0], st[s][3][1]), fmaxf(st[s][3][2], st[s][3][3])); \
      float pm = fmaxf(fmaxf(a0, a1), fmaxf(a2, a3)); /* lane-local max */                \
      if (!__all(pm - m[s] <= 8.0f)) { /* rare: full reduce + rescale */                  \
        float pmf = fmaxf(pm, __shfl_xor(pm, 16));                                        \
        pmf = fmaxf(pmf, __shfl_xor(pmf, 32));                                            \
        const float mn = fmaxf(m[s], pmf);                                                \
        const float al = __builtin_amdgcn_exp2f(m[s] - mn);                               \
        l[s] *= al;                                                                       \
        m[s] = mn;                                                                        \
        _Pragma("unroll") for (int nb = 0; nb < 4; ++nb)                                  \
            _Pragma("unroll") for (int r = 0; r < 4; ++r) o[s][nb][r] *= al;              \
      }                                                                                   \
      float rs = 0.f;                                                                     \
      _Pragma("unroll") for (int nb = 0; nb < 4; ++nb) {                                  \
        float p0 = __builtin_amdgcn_exp2f(st[s][nb][0] - m[s]);                           \
        float p1 = __builtin_amdgcn_exp2f(st[s][nb][1] - m[s]);                           \
        float p2 = __builtin_amdgcn_exp2f(st[s][nb][2] - m[s]);                           \
        float p3 = __builtin_amdgcn_exp2f(st[s][nb][3] - m[s]);                           \
        rs += (p0 + p1) + (p2 + p3);                                                      \
        uint2 w;                                                                          \
        w.x = cvt_pk_bf16(p0, p1);                                                        \
        w.y = cvt_pk_bf16(p2, p3);                                                        \
        *reinterpret_cast<uint2*>(P_lds + (s * 16 + l15) * 64 +                           \
                                  ((nb * 16 + g * 4) ^ swz)) = w;                         \
      }                                                                                   \
      l[s] += rs;                                                                         \
    }                                                                                     \
    s16x8 pa[2][2];                                                                       \
    _Pragma("unroll") for (int s = 0; s < 2; ++s)                                         \
        _Pragma("unroll") for (int c = 0; c < 2; ++c)                                     \
            pa[s][c] = *reinterpret_cast<const s16x8*>(P_lds + (s * 16 + l15) * 64 +      \
                                                       ((c * 32 + g * 8) ^ swz));         \
    _Pragma("unroll") for (int nb = 0; nb < 4; ++nb) {                                    \
      _Pragma("unroll") for (int s = 0; s < 2; ++s) {                                     \
        o[s][nb] = __builtin_amdgcn_mfma_f32_16x16x32_bf16(vf[nb * 2 + 0], pa[s][0],      \
                                                           o[s][nb], 0, 0, 0);            \
        o[s][nb] = __builtin_amdgcn_mfma_f32_16x16x32_bf16(vf[nb * 2 + 1], pa[s][1],      \
                                                           o[s][nb], 0, 0, 0);            \
      }                                                                                   \
    }                                                                                     \
  } while (0)

  int kt = 0;
  for (;;) {
    ATTN_STEP(kfA, kfB, kt);
    if (++kt > ktmax) break;
    ATTN_STEP(kfB, kfA, kt);
    if (++kt > ktmax) break;
  }
#undef ATTN_STEP

  // Epilogue: reduce partial l across the 4 lane-groups, then store O^T rows.
  const int b = bh >> 3, h = bh & 7;
#pragma unroll
  for (int s = 0; s < 2; ++s) {
    float ls = l[s];
    ls += __shfl_xor(ls, 16);
    ls += __shfl_xor(ls, 32);
    const float linv = 1.0f / ls;
    const size_t rowo = (size_t)(b * 4096 + qw + s * 16 + l15) * 512 + h * 64;
#pragma unroll
    for (int nb = 0; nb < 4; ++nb) {
      uint2 pk;
      pk.x = cvt_pk_bf16(o[s][nb][0] * linv, o[s][nb][1] * linv);
      pk.y = cvt_pk_bf16(o[s][nb][2] * linv, o[s][nb][3] * linv);
      *reinterpret_cast<uint2*>(&O[rowo + nb * 16 + g * 4]) = pk;
    }
  }
}

extern "C" void kernel_launch(void* const* d_in, const int* in_sizes, int n_in,
                              void* d_out, int out_size, void* d_ws, size_t ws_size,
                              hipStream_t stream) {
  const float* x = (const float*)d_in[0];       // [2,4096,512]
  const float* w_qkv = (const float*)d_in[1];   // [1536,512]
  const float* w_proj = (const float*)d_in[2];  // [512,512]
  const float* b_proj = (const float*)d_in[3];  // [512]
  float* out = (float*)d_out;                   // [2,4096,512]

  ushort* xb = (ushort*)d_ws;                       // 8192*512
  ushort* wqkvb = xb + (size_t)8192 * 512;          // 1536*512
  ushort* wprojb = wqkvb + (size_t)1536 * 512;      // 512*512
  ushort* qws = wprojb + (size_t)512 * 512;         // 16*4096*64
  ushort* kws = qws + (size_t)16 * 4096 * 64;
  ushort* vtws = kws + (size_t)16 * 4096 * 64;
  ushort* ows = vtws + (size_t)16 * 4096 * 64;      // 8192*512

  cvt_kernel<<<4096, 256, 0, stream>>>(x, xb, 8192 * 512 / 4);
  cvt_kernel<<<768, 256, 0, stream>>>(w_qkv, wqkvb, 1536 * 512 / 4);
  cvt_kernel<<<256, 256, 0, stream>>>(w_proj, wprojb, 512 * 512 / 4);

  gemm_bt<0><<<dim3(12, 64), 256, 0, stream>>>(xb, wqkvb, qws, kws, vtws, nullptr, nullptr);

  attn_kernel<<<dim3(128, 16), 64, 0, stream>>>(qws, kws, vtws, ows);

  gemm_bt<1><<<dim3(4, 64), 256, 0, stream>>>(ows, wprojb, nullptr, nullptr, nullptr, out,
                                              b_proj);
}